// Round 10
// baseline (123.002 us; speedup 1.0000x reference)
//
#include <hip/hip_runtime.h>

#define DD 128
#define FF 512
#define BAGS 5000
#define TASK_CAP 32

// Monotonic uint key for f32: preserves float ordering under unsigned compare.
__device__ __forceinline__ unsigned fkey(float f) {
    unsigned u = __float_as_uint(f);
    return (u & 0x80000000u) ? ~u : (u | 0x80000000u);
}
// Inverse of fkey (bijective).
__device__ __forceinline__ float fkey_inv(unsigned k) {
    unsigned u = (k & 0x80000000u) ? (k & 0x7FFFFFFFu) : ~k;
    return __uint_as_float(u);
}

// Pathological-only: zero-fill outputs of an empty bag (single lane, serial).
__device__ void zero_bag(int bg, float* oM, float* oInst, float* oZ,
                         float* oMu, float* oStd) {
    oM[bg] = 0.f;
    const float4 z4 = make_float4(0.f, 0.f, 0.f, 0.f);
    float4* pi = (float4*)(oInst + (long long)bg * FF);
    for (int k = 0; k < FF / 4; ++k) pi[k] = z4;
    float4* pz = (float4*)(oZ + (long long)bg * DD);
    float4* pm = (float4*)(oMu + (long long)bg * DD);
    float4* ps = (float4*)(oStd + (long long)bg * DD);
    for (int k = 0; k < DD / 4; ++k) { pz[k] = z4; pm[k] = z4; ps[k] = z4; }
}

// Fallback when the LDS task list overflows (never in practice): single-lane copy.
__device__ void lane_gather(int bg, unsigned long long p, int N,
                            const float* z, const float* inst, const float* mu,
                            const float* stdv, float* oM, float* oInst,
                            float* oZ, float* oMu, float* oStd) {
    long long ac = N - 1 - (int)(unsigned)(p & 0xFFFFFFFFull);
    oM[bg] = fkey_inv((unsigned)(p >> 32));
    for (int k = 0; k < FF; ++k) oInst[(long long)bg * FF + k] = inst[ac * FF + k];
    for (int k = 0; k < DD; ++k) {
        oZ[(long long)bg * DD + k]  = z[ac * DD + k];
        oMu[(long long)bg * DD + k] = mu[ac * DD + k];
        oStd[(long long)bg * DD + k] = stdv[ac * DD + k];
    }
}

// One dispatch: loc matvec + per-bag argmax + gather, fused.
// Interior bags (fully inside a block's 256 rows): direct gather, no atomics.
// Spanning bags: lock-free last-arriver protocol via device-scope atomics
// (post start/end/max, fence, add rowcount; the completing adder gathers).
__global__ __launch_bounds__(256) void fused_kernel(
    const float* __restrict__ z, const int* __restrict__ bag,
    const float* __restrict__ inst, const float* __restrict__ mu,
    const float* __restrict__ stdv, const float* __restrict__ W,
    const float* __restrict__ bptr,
    float* __restrict__ oM, float* __restrict__ oInst, float* __restrict__ oZ,
    float* __restrict__ oMu, float* __restrict__ oStd, float* __restrict__ loc,
    unsigned long long* __restrict__ packed, unsigned* __restrict__ bagstart,
    unsigned* __restrict__ bagend, unsigned* __restrict__ done, int N)
{
    __shared__ unsigned long long keyA[256];
    __shared__ int bagA[256];
    __shared__ int s_prev, s_next, s_ntask;
    __shared__ int taskBag[TASK_CAP];
    __shared__ unsigned long long taskKey[TASK_CAP];

    int tid  = threadIdx.x;
    int lane = tid & 63;
    int wave = tid >> 6;
    long long rowbase = (long long)blockIdx.x * 256;

    if (tid == 0) {
        s_prev = (rowbase > 0) ? bag[rowbase - 1] : -1;
        long long nr = rowbase + 256;
        s_next = (nr < N) ? bag[nr] : BAGS;
        s_ntask = 0;
    }

    // ---- matvec (R8-proven octet pattern + in-wave transpose) ----
    int o = lane & 7;
    int rowslot = lane >> 3;
    long long wbase = rowbase + (long long)wave * 64;
    float4 wk[4];
    #pragma unroll
    for (int j = 0; j < 4; ++j) wk[j] = ((const float4*)W)[o + 8 * j];
    float bb = bptr[0];

    float myloc = 0.f;
    #pragma unroll
    for (int t = 0; t < 8; ++t) {
        long long row = wbase + t * 8 + rowslot;
        float4 acc = make_float4(0.f, 0.f, 0.f, 0.f);
        if (row < N) {
            const float4* zr = (const float4*)(z + row * DD);
            #pragma unroll
            for (int j = 0; j < 4; ++j) {
                float4 zv = zr[o + 8 * j];
                acc.x = fmaf(zv.x, wk[j].x, acc.x);
                acc.y = fmaf(zv.y, wk[j].y, acc.y);
                acc.z = fmaf(zv.z, wk[j].z, acc.z);
                acc.w = fmaf(zv.w, wk[j].w, acc.w);
            }
        }
        float sd = (acc.x + acc.y) + (acc.z + acc.w);
        sd += __shfl_xor(sd, 1, 64);
        sd += __shfl_xor(sd, 2, 64);
        sd += __shfl_xor(sd, 4, 64);
        float v = __shfl(sd, (lane & 7) * 8, 64);
        if (t == (lane >> 3)) myloc = v;
    }

    long long myrow = wbase + lane;
    bool valid = myrow < N;
    myloc += bb;
    int mybag = BAGS;                       // sentinel for invalid lanes
    unsigned long long mykey = 0ull;
    if (valid) {
        loc[myrow] = myloc;                 // coalesced 256B per wave
        mybag = bag[myrow];                 // coalesced
        mykey = ((unsigned long long)fkey(myloc) << 32) | (unsigned)(N - 1 - (int)myrow);
    }

    // ---- in-wave segmented suffix-max (coverage [lane, wave_end ∩ segment]) ----
    #pragma unroll
    for (int off = 1; off <= 32; off <<= 1) {
        int src = lane + off;
        int cl = src < 64 ? src : lane;
        unsigned long long ok = __shfl(mykey, cl, 64);
        int ob = __shfl(mybag, cl, 64);
        if (src < 64 && ob == mybag && ok > mykey) mykey = ok;
    }
    keyA[tid] = mykey;
    bagA[tid] = mybag;
    __syncthreads();

    // ---- per-bag logic ----
    int pb = (tid == 0) ? s_prev : bagA[tid - 1];
    bool rep = valid && (tid == 0 || pb != mybag);   // in-block segment start

    if (rep) {
        // extend coverage to segment end across following waves (lane-0 values)
        for (int w2 = wave + 1; w2 < 4; ++w2) {
            if (bagA[w2 * 64] != mybag) break;
            unsigned long long ok = keyA[w2 * 64];
            if (ok > mykey) mykey = ok;
        }
    }

    // empty-bag gap fill (pathological; exact coverage incl. leading/trailing gaps)
    {
        int hi = (mybag < BAGS ? mybag : BAGS) - 1;
        for (int bg = pb + 1; bg <= hi; ++bg)
            zero_bag(bg, oM, oInst, oZ, oMu, oStd);
        if (valid && tid == 255 && rowbase + 256 >= N && mybag < BAGS - 1)
            for (int bg = mybag + 1; bg < BAGS; ++bg)
                zero_bag(bg, oM, oInst, oZ, oMu, oStd);
    }

    if (rep) {
        int lastbagblk = bagA[255];
        bool gfirst = (tid > 0) || (mybag != s_prev);
        bool reaches_end = (mybag == lastbagblk);
        bool glast = !reaches_end || (s_next != mybag);

        if (gfirst && glast) {
            // interior bag: block-local max is global; gather directly, no atomics
            int idx = atomicAdd(&s_ntask, 1);
            if (idx < TASK_CAP) { taskBag[idx] = mybag; taskKey[idx] = mykey; }
            else lane_gather(mybag, mykey, N, z, inst, mu, stdv, oM, oInst, oZ, oMu, oStd);
        } else {
            // spanning piece: lock-free last-arriver protocol
            int t2 = tid;
            while (t2 + 1 < 256 && bagA[t2 + 1] == mybag) ++t2;
            int C = t2 - tid + 1;
            if (gfirst) atomicMax(&bagstart[mybag], (unsigned)(N - (int)(rowbase + tid)));
            if (glast)  atomicMax(&bagend[mybag],   (unsigned)(rowbase + t2 + 1));
            atomicMax(&packed[mybag], mykey);
            __threadfence();
            unsigned total = atomicAdd(&done[mybag], (unsigned)C) + (unsigned)C;
            __threadfence();
            unsigned bs = atomicMax(&bagstart[mybag], 0u);
            unsigned be = atomicMax(&bagend[mybag], 0u);
            if (bs != 0u && be != 0u &&
                (long long)total == (long long)be + (long long)bs - (long long)N) {
                unsigned long long K = atomicMax(&packed[mybag], 0ull);
                int idx = atomicAdd(&s_ntask, 1);
                if (idx < TASK_CAP) { taskBag[idx] = mybag; taskKey[idx] = K; }
                else lane_gather(mybag, K, N, z, inst, mu, stdv, oM, oInst, oZ, oMu, oStd);
            }
        }
    }
    __syncthreads();

    // ---- block-wide gather of queued bags ----
    int nt = s_ntask; if (nt > TASK_CAP) nt = TASK_CAP;
    for (int q = 0; q < nt; ++q) {
        int bg = taskBag[q];
        unsigned long long p = taskKey[q];
        long long ac = N - 1 - (int)(unsigned)(p & 0xFFFFFFFFull);
        int t = tid;
        if (t < 128) {
            ((float4*)(oInst + (long long)bg * FF))[t] = ((const float4*)(inst + ac * FF))[t];
        } else if (t < 160) {
            int k = t - 128;
            ((float4*)(oZ + (long long)bg * DD))[k] = ((const float4*)(z + ac * DD))[k];
        } else if (t < 192) {
            int k = t - 160;
            ((float4*)(oMu + (long long)bg * DD))[k] = ((const float4*)(mu + ac * DD))[k];
        } else if (t < 224) {
            int k = t - 192;
            ((float4*)(oStd + (long long)bg * DD))[k] = ((const float4*)(stdv + ac * DD))[k];
        } else if (t == 224) {
            oM[bg] = fkey_inv((unsigned)(p >> 32));
        }
    }
}

extern "C" void kernel_launch(void* const* d_in, const int* in_sizes, int n_in,
                              void* d_out, int out_size, void* d_ws, size_t ws_size,
                              hipStream_t stream) {
    const float* z    = (const float*)d_in[0];
    const int*   bag  = (const int*)d_in[1];
    const float* inst = (const float*)d_in[2];
    const float* mu   = (const float*)d_in[3];
    const float* stdv = (const float*)d_in[4];
    const float* W    = (const float*)d_in[5];
    const float* b    = (const float*)d_in[6];
    int N = in_sizes[1];

    float* out = (float*)d_out;
    // Output layout (flat, return order): M | max_instances | max_z_ins | loc_ins | mu | std
    long long off_inst = BAGS;
    long long off_z    = off_inst + (long long)BAGS * FF;
    long long off_loc  = off_z    + (long long)BAGS * DD;
    long long off_mu   = off_loc  + N;
    long long off_std  = off_mu   + (long long)BAGS * DD;

    // ws layout: packed u64[BAGS] | bagstart u32[BAGS] | bagend u32[BAGS] | done u32[BAGS]
    unsigned long long* packed = (unsigned long long*)d_ws;
    unsigned* bagstart = (unsigned*)((char*)d_ws + BAGS * 8);
    unsigned* bagend   = (unsigned*)((char*)d_ws + BAGS * 8 + BAGS * 4);
    unsigned* done     = (unsigned*)((char*)d_ws + BAGS * 8 + BAGS * 8);

    hipMemsetAsync(d_ws, 0, BAGS * 20, stream);
    int blocks = (N + 255) / 256;
    fused_kernel<<<blocks, 256, 0, stream>>>(
        z, bag, inst, mu, stdv, W, b,
        out, out + off_inst, out + off_z, out + off_mu, out + off_std,
        out + off_loc,
        packed, bagstart, bagend, done, N);
}

// Round 11
// 37.732 us; speedup vs baseline: 3.2599x; 3.2599x over previous
//
#include <hip/hip_runtime.h>

#define DD 128
#define FF 512
#define BAGS 5000

// Monotonic uint key for f32: preserves float ordering under unsigned compare.
__device__ __forceinline__ unsigned fkey(float f) {
    unsigned u = __float_as_uint(f);
    return (u & 0x80000000u) ? ~u : (u | 0x80000000u);
}
// Inverse of fkey (bijective).
__device__ __forceinline__ float fkey_inv(unsigned k) {
    unsigned u = (k & 0x80000000u) ? (k & 0x7FFFFFFFu) : ~k;
    return __uint_as_float(u);
}

// loc = z@W + b, 8 lanes/row octet matvec (R8-proven), coalesced loc store.
// Bag boundaries -> start[] by PLAIN STORES (sorted bag_idx): the lane at each
// boundary writes start[pb+1..cb] = row (gap-fill covers empty bags); row N-1
// writes start[last+1..BAGS] = N. No atomics, no init required.
__global__ __launch_bounds__(256) void loc_kernel(
    const float* __restrict__ z, const int* __restrict__ bag,
    const float* __restrict__ W, const float* __restrict__ b,
    float* __restrict__ loc, int* __restrict__ start, int N)
{
    int tid  = threadIdx.x;
    int lane = tid & 63;
    int wave = tid >> 6;              // 0..3
    int o    = lane & 7;              // octet position within row
    int rowslot = lane >> 3;          // 0..7

    long long wbase = (long long)blockIdx.x * 256 + wave * 64;

    float4 wk[4];                     // this lane's 4 W chunks (k = o + 8j)
    #pragma unroll
    for (int j = 0; j < 4; ++j) wk[j] = ((const float4*)W)[o + 8 * j];
    float bb = b[0];

    float myloc = 0.f;
    #pragma unroll
    for (int t = 0; t < 8; ++t) {
        long long row = wbase + t * 8 + rowslot;
        float4 acc = make_float4(0.f, 0.f, 0.f, 0.f);
        if (row < N) {
            const float4* zr = (const float4*)(z + row * DD);
            #pragma unroll
            for (int j = 0; j < 4; ++j) {
                float4 zv = zr[o + 8 * j];
                acc.x = fmaf(zv.x, wk[j].x, acc.x);
                acc.y = fmaf(zv.y, wk[j].y, acc.y);
                acc.z = fmaf(zv.z, wk[j].z, acc.z);
                acc.w = fmaf(zv.w, wk[j].w, acc.w);
            }
        }
        float sd = (acc.x + acc.y) + (acc.z + acc.w);
        sd += __shfl_xor(sd, 1, 64);   // octet-local reduce
        sd += __shfl_xor(sd, 2, 64);
        sd += __shfl_xor(sd, 4, 64);
        // in-wave transpose: lane l takes the value for row wbase+l
        float v = __shfl(sd, (lane & 7) * 8, 64);
        if (t == (lane >> 3)) myloc = v;
    }

    long long row = wbase + lane;
    bool valid = row < N;
    if (valid) {
        loc[row] = myloc + bb;              // coalesced 256B store per wave
        int cb = bag[row];                  // coalesced load
        int pb = __shfl_up(cb, 1, 64);
        if (lane == 0) pb = (row > 0) ? bag[row - 1] : -1;
        if (row == 0 || cb != pb) {
            for (int bg = (row == 0 ? 0 : pb + 1); bg <= cb; ++bg)
                start[bg] = (int)row;       // gap-fill: empty bags get s==e
        }
        if (row == N - 1) {
            for (int bg = cb + 1; bg <= BAGS; ++bg)
                start[bg] = N;
        }
    }
}

// One block per bag: wave 0 re-reads the bag's loc slice (L2-hot) and finds
// packed max (fkey, N-1-row); all 256 threads then gather (zeros if empty).
__global__ __launch_bounds__(256) void gather_kernel(
    const float* __restrict__ z, const float* __restrict__ inst,
    const float* __restrict__ mu, const float* __restrict__ stdv,
    const float* __restrict__ loc, const int* __restrict__ start,
    float* __restrict__ oM, float* __restrict__ oInst, float* __restrict__ oZ,
    float* __restrict__ oMu, float* __restrict__ oStd, int N)
{
    __shared__ unsigned long long s_res;
    __shared__ int s_se[2];

    int bagi = blockIdx.x;
    int tid = threadIdx.x;
    if (tid < 2) s_se[tid] = start[bagi + tid];
    __syncthreads();
    int s = s_se[0], e = s_se[1];

    if (tid < 64) {
        unsigned long long best = 0ull;
        for (int r = s + tid; r < e; r += 64) {
            unsigned long long key =
                ((unsigned long long)fkey(loc[r]) << 32) | (unsigned)(N - 1 - r);
            if (key > best) best = key;
        }
        #pragma unroll
        for (int off = 32; off >= 1; off >>= 1) {
            unsigned long long o = __shfl_xor(best, off, 64);
            if (o > best) best = o;
        }
        if (tid == 0) s_res = best;
    }
    __syncthreads();

    unsigned long long p = s_res;
    bool empty = (e <= s);
    long long ac = empty ? 0 : (long long)(N - 1 - (int)(unsigned)(p & 0xFFFFFFFFull));
    const float4 zero4 = make_float4(0.f, 0.f, 0.f, 0.f);
    int t = tid;
    if (t < 128) {
        float4 v = empty ? zero4 : ((const float4*)(inst + ac * FF))[t];
        ((float4*)(oInst + (long long)bagi * FF))[t] = v;
    } else if (t < 160) {
        int k = t - 128;
        float4 v = empty ? zero4 : ((const float4*)(z + ac * DD))[k];
        ((float4*)(oZ + (long long)bagi * DD))[k] = v;
    } else if (t < 192) {
        int k = t - 160;
        float4 v = empty ? zero4 : ((const float4*)(mu + ac * DD))[k];
        ((float4*)(oMu + (long long)bagi * DD))[k] = v;
    } else if (t < 224) {
        int k = t - 192;
        float4 v = empty ? zero4 : ((const float4*)(stdv + ac * DD))[k];
        ((float4*)(oStd + (long long)bagi * DD))[k] = v;
    } else if (t == 224) {
        oM[bagi] = empty ? 0.f : fkey_inv((unsigned)(p >> 32));
    }
}

extern "C" void kernel_launch(void* const* d_in, const int* in_sizes, int n_in,
                              void* d_out, int out_size, void* d_ws, size_t ws_size,
                              hipStream_t stream) {
    const float* z    = (const float*)d_in[0];
    const int*   bag  = (const int*)d_in[1];
    const float* inst = (const float*)d_in[2];
    const float* mu   = (const float*)d_in[3];
    const float* stdv = (const float*)d_in[4];
    const float* W    = (const float*)d_in[5];
    const float* b    = (const float*)d_in[6];
    int N = in_sizes[1];

    float* out = (float*)d_out;
    // Output layout (flat, return order): M | max_instances | max_z_ins | loc_ins | mu | std
    long long off_inst = BAGS;
    long long off_z    = off_inst + (long long)BAGS * FF;
    long long off_loc  = off_z    + (long long)BAGS * DD;
    long long off_mu   = off_loc  + N;
    long long off_std  = off_mu   + (long long)BAGS * DD;

    int* startArr = (int*)d_ws;       // (BAGS+1) ints, fully written every call
    float* loc = out + off_loc;

    int blocks = (N + 255) / 256;
    loc_kernel<<<blocks, 256, 0, stream>>>(z, bag, W, b, loc, startArr, N);
    gather_kernel<<<BAGS, 256, 0, stream>>>(z, inst, mu, stdv, loc, startArr,
                                            out, out + off_inst, out + off_z,
                                            out + off_mu, out + off_std, N);
}

// Round 12
// 37.415 us; speedup vs baseline: 3.2875x; 1.0085x over previous
//
#include <hip/hip_runtime.h>

#define DD 128
#define FF 512
#define BAGS 5000

typedef float f4 __attribute__((ext_vector_type(4)));

// Monotonic uint key for f32: preserves float ordering under unsigned compare.
__device__ __forceinline__ unsigned fkey(float f) {
    unsigned u = __float_as_uint(f);
    return (u & 0x80000000u) ? ~u : (u | 0x80000000u);
}
// Inverse of fkey (bijective).
__device__ __forceinline__ float fkey_inv(unsigned k) {
    unsigned u = (k & 0x80000000u) ? (k & 0x7FFFFFFFu) : ~k;
    return __uint_as_float(u);
}

// loc = z@W + b, 8 lanes/row octet matvec; wave reads flat chunk t*64+lane
// (perfectly linear 1KB/instr). z loads nontemporal (read-once stream).
// Bag boundaries -> start[] by PLAIN STORES (sorted bag_idx), gap-filled.
__global__ __launch_bounds__(256) void loc_kernel(
    const float* __restrict__ z, const int* __restrict__ bag,
    const float* __restrict__ W, const float* __restrict__ b,
    float* __restrict__ loc, int* __restrict__ start, int N)
{
    int tid  = threadIdx.x;
    int lane = tid & 63;
    int wave = tid >> 6;              // 0..3
    int o    = lane & 7;              // octet position within row
    int rowslot = lane >> 3;          // 0..7

    long long wbase = (long long)blockIdx.x * 256 + wave * 64;

    f4 wk[4];                         // this lane's 4 W chunks (k = o + 8j)
    #pragma unroll
    for (int j = 0; j < 4; ++j) wk[j] = ((const f4*)W)[o + 8 * j];
    float bb = b[0];

    float myloc = 0.f;
    #pragma unroll
    for (int t = 0; t < 8; ++t) {
        long long row = wbase + t * 8 + rowslot;
        f4 acc = (f4)(0.f);
        if (row < N) {
            const f4* zr = (const f4*)(z + row * DD);
            #pragma unroll
            for (int j = 0; j < 4; ++j) {
                f4 zv = __builtin_nontemporal_load(&zr[o + 8 * j]);
                acc.x = fmaf(zv.x, wk[j].x, acc.x);
                acc.y = fmaf(zv.y, wk[j].y, acc.y);
                acc.z = fmaf(zv.z, wk[j].z, acc.z);
                acc.w = fmaf(zv.w, wk[j].w, acc.w);
            }
        }
        float sd = (acc.x + acc.y) + (acc.z + acc.w);
        sd += __shfl_xor(sd, 1, 64);   // octet-local reduce
        sd += __shfl_xor(sd, 2, 64);
        sd += __shfl_xor(sd, 4, 64);
        // in-wave transpose: lane l takes the value for row wbase+l
        float v = __shfl(sd, (lane & 7) * 8, 64);
        if (t == (lane >> 3)) myloc = v;
    }

    long long row = wbase + lane;
    bool valid = row < N;
    if (valid) {
        loc[row] = myloc + bb;              // coalesced 256B store per wave
        int cb = bag[row];                  // coalesced load
        int pb = __shfl_up(cb, 1, 64);
        if (lane == 0) pb = (row > 0) ? bag[row - 1] : -1;
        if (row == 0 || cb != pb) {
            for (int bg = (row == 0 ? 0 : pb + 1); bg <= cb; ++bg)
                start[bg] = (int)row;       // gap-fill: empty bags get s==e
        }
        if (row == N - 1) {
            for (int bg = cb + 1; bg <= BAGS; ++bg)
                start[bg] = N;
        }
    }
}

// One block per bag: wave 0 re-reads the bag's loc slice and finds packed max;
// all 256 threads gather. Row reads + output stores nontemporal (touch-once).
__global__ __launch_bounds__(256) void gather_kernel(
    const float* __restrict__ z, const float* __restrict__ inst,
    const float* __restrict__ mu, const float* __restrict__ stdv,
    const float* __restrict__ loc, const int* __restrict__ start,
    float* __restrict__ oM, float* __restrict__ oInst, float* __restrict__ oZ,
    float* __restrict__ oMu, float* __restrict__ oStd, int N)
{
    __shared__ unsigned long long s_res;
    __shared__ int s_se[2];

    int bagi = blockIdx.x;
    int tid = threadIdx.x;
    if (tid < 2) s_se[tid] = start[bagi + tid];
    __syncthreads();
    int s = s_se[0], e = s_se[1];

    if (tid < 64) {
        unsigned long long best = 0ull;
        for (int r = s + tid; r < e; r += 64) {
            unsigned long long key =
                ((unsigned long long)fkey(loc[r]) << 32) | (unsigned)(N - 1 - r);
            if (key > best) best = key;
        }
        #pragma unroll
        for (int off = 32; off >= 1; off >>= 1) {
            unsigned long long o = __shfl_xor(best, off, 64);
            if (o > best) best = o;
        }
        if (tid == 0) s_res = best;
    }
    __syncthreads();

    unsigned long long p = s_res;
    bool empty = (e <= s);
    long long ac = empty ? 0 : (long long)(N - 1 - (int)(unsigned)(p & 0xFFFFFFFFull));
    const f4 zero4 = (f4)(0.f);
    int t = tid;
    if (t < 128) {
        f4 v = empty ? zero4 : __builtin_nontemporal_load(&((const f4*)(inst + ac * FF))[t]);
        __builtin_nontemporal_store(v, &((f4*)(oInst + (long long)bagi * FF))[t]);
    } else if (t < 160) {
        int k = t - 128;
        f4 v = empty ? zero4 : __builtin_nontemporal_load(&((const f4*)(z + ac * DD))[k]);
        __builtin_nontemporal_store(v, &((f4*)(oZ + (long long)bagi * DD))[k]);
    } else if (t < 192) {
        int k = t - 160;
        f4 v = empty ? zero4 : __builtin_nontemporal_load(&((const f4*)(mu + ac * DD))[k]);
        __builtin_nontemporal_store(v, &((f4*)(oMu + (long long)bagi * DD))[k]);
    } else if (t < 224) {
        int k = t - 192;
        f4 v = empty ? zero4 : __builtin_nontemporal_load(&((const f4*)(stdv + ac * DD))[k]);
        __builtin_nontemporal_store(v, &((f4*)(oStd + (long long)bagi * DD))[k]);
    } else if (t == 224) {
        oM[bagi] = empty ? 0.f : fkey_inv((unsigned)(p >> 32));
    }
}

extern "C" void kernel_launch(void* const* d_in, const int* in_sizes, int n_in,
                              void* d_out, int out_size, void* d_ws, size_t ws_size,
                              hipStream_t stream) {
    const float* z    = (const float*)d_in[0];
    const int*   bag  = (const int*)d_in[1];
    const float* inst = (const float*)d_in[2];
    const float* mu   = (const float*)d_in[3];
    const float* stdv = (const float*)d_in[4];
    const float* W    = (const float*)d_in[5];
    const float* b    = (const float*)d_in[6];
    int N = in_sizes[1];

    float* out = (float*)d_out;
    // Output layout (flat, return order): M | max_instances | max_z_ins | loc_ins | mu | std
    long long off_inst = BAGS;
    long long off_z    = off_inst + (long long)BAGS * FF;
    long long off_loc  = off_z    + (long long)BAGS * DD;
    long long off_mu   = off_loc  + N;
    long long off_std  = off_mu   + (long long)BAGS * DD;

    int* startArr = (int*)d_ws;       // (BAGS+1) ints, fully written every call
    float* loc = out + off_loc;

    int blocks = (N + 255) / 256;
    loc_kernel<<<blocks, 256, 0, stream>>>(z, bag, W, b, loc, startArr, N);
    gather_kernel<<<BAGS, 256, 0, stream>>>(z, inst, mu, stdv, loc, startArr,
                                            out, out + off_inst, out + off_z,
                                            out + off_mu, out + off_std, N);
}